// Round 1
// 250.012 us; speedup vs baseline: 1.0726x; 1.0726x over previous
//
#include <hip/hip_runtime.h>

// GCNFast: out[b,s,t,d] = relu( sum_j relu(AA[i%64,j%64]*GCW[i,j]) * X[j,b,d] + GCB[i,d] )
// 3-phase -> 2-dispatch:
//   (1) fused prep: blocks [0,4096) build A=relu(AA*GCW)->bf16 reading only the
//       64x64 AA tile (AA_mask[i,j]=AA[i%64,j%64] -- skip 67MB of redundant mask),
//       blocks [4096,5120) transpose h -> XT bf16 with COALESCED writes
//       (8 lanes cover one full 128B XT row; old version scattered 16B x 64 lanes).
//   (2) m97-style MFMA GEMM (unchanged): 128x128 tile, BK=64, global_load_lds
//       dwordx4 staging, XOR chunk swizzle, fused bias+relu+permute epilogue.
// Fallback to fused single-kernel path if ws_size < 50.3 MB.

#define NC 64
#define NS 64
#define NT 64
#define DH 128
#define BATCH 16
#define MDIM 4096
#define KDIM 4096
#define TM 128
#define TK 64

typedef __attribute__((ext_vector_type(8))) short short8;
typedef __attribute__((ext_vector_type(4))) float floatx4;

__device__ __forceinline__ unsigned short f2bf(float f) {
    union { float f; unsigned int i; } v; v.f = f;
    return (unsigned short)((v.i + 0x7fffu + ((v.i >> 16) & 1u)) >> 16);
}
__device__ __forceinline__ void async16(const void* g, void* l) {
    __builtin_amdgcn_global_load_lds(
        (const __attribute__((address_space(1))) void*)g,
        (__attribute__((address_space(3))) void*)l, 16, 0, 0);
}

// ---- fused prep ----
// blocks [0, MDIM):       A[i][:] = relu(AA[i%64][j%64] * GCW[i][j]) -> bf16
// blocks [MDIM, MDIM+1024): XT[(b*128+d)][t*64+c] = bf16(h[b,c,t,d])
__global__ __launch_bounds__(256)
void prep(const float* __restrict__ aam, const float* __restrict__ gcw,
          const float* __restrict__ hmat,
          unsigned short* __restrict__ Abf, unsigned short* __restrict__ XT)
{
    const int tid = threadIdx.x;
    if ((int)blockIdx.x < MDIM) {
        // ---- A-prep: one row i per block; mask row is 64 floats, L2-resident ----
        const int i = blockIdx.x;
        __shared__ float sm[64];
        if (tid < 64) sm[tid] = aam[(size_t)(i & 63) * KDIM + tid];
        __syncthreads();
        const size_t base = (size_t)i * KDIM + tid * 16;
        floatx4 w0 = *(const floatx4*)(gcw + base);
        floatx4 w1 = *(const floatx4*)(gcw + base + 4);
        floatx4 w2 = *(const floatx4*)(gcw + base + 8);
        floatx4 w3 = *(const floatx4*)(gcw + base + 12);
        // j = tid*16 + e  ->  j%64 = (tid&3)*16 + e   (16 divides 64)
        const float* m = &sm[(tid & 3) * 16];
        short8 p0, p1;
#pragma unroll
        for (int e = 0; e < 4; ++e) {
            float v0 = m[e]      * w0[e]; v0 = v0 > 0.f ? v0 : 0.f;
            float v1 = m[e + 4]  * w1[e]; v1 = v1 > 0.f ? v1 : 0.f;
            float v2 = m[e + 8]  * w2[e]; v2 = v2 > 0.f ? v2 : 0.f;
            float v3 = m[e + 12] * w3[e]; v3 = v3 > 0.f ? v3 : 0.f;
            p0[e]     = (short)f2bf(v0);
            p0[e + 4] = (short)f2bf(v1);
            p1[e]     = (short)f2bf(v2);
            p1[e + 4] = (short)f2bf(v3);
        }
        *(short8*)(Abf + base)     = p0;
        *(short8*)(Abf + base + 8) = p1;
    } else {
        // ---- X-transpose: one (b,t) per block; 8 lanes write one full 128B row ----
        const int blk = blockIdx.x - MDIM;
        const int b = blk >> 6;
        const int t = blk & 63;
        const int c0 = (tid & 7) * 8;   // c-chunk of 8 -> 16B store
        const int d0 = tid >> 3;        // 0..31, +it*32
#pragma unroll
        for (int it = 0; it < 4; ++it) {
            const int d = d0 + it * 32;
            short8 p;
#pragma unroll
            for (int e = 0; e < 8; ++e) {
                float v = hmat[(((size_t)b * NC + (c0 + e)) * NT + t) * DH + d];
                p[e] = (short)f2bf(v);
            }
            *(short8*)(XT + ((size_t)(b * DH + d)) * KDIM + t * 64 + c0) = p;
        }
    }
}

// ---- GEMM C[4096, b*128+d] with global_load_lds + swizzle (UNCHANGED) ----
__global__ __launch_bounds__(256, 2)
void gemm(const unsigned short* __restrict__ Abf,
          const unsigned short* __restrict__ XT,
          const float* __restrict__ gcb,
          float* __restrict__ out)
{
    __shared__ short sA[TM * TK];   // [128 rows][64 k] bf16, chunk-swizzled
    __shared__ short sX[TM * TK];

    const int tid = threadIdx.x;
    const int bid = blockIdx.x;
    const int mp  = (bid & 7) * 4 + (bid >> 7);   // m-panel 0..31 (XCD swizzle)
    const int b   = (bid >> 3) & 15;
    const int i0  = mp * TM;

    const int lane = tid & 63;
    const int w    = tid >> 6;
    const int wm = (w >> 1) * 64;
    const int wn = (w & 1) * 64;
    const int l15 = lane & 15;
    const int q   = lane >> 4;

    const int srow = lane >> 3;   // staging: row within 8-row group
    const int schk = lane & 7;    // staging: 16B chunk within 128B row

    floatx4 acc[4][4];
#pragma unroll
    for (int mi = 0; mi < 4; ++mi)
#pragma unroll
        for (int ni = 0; ni < 4; ++ni)
            acc[mi][ni] = (floatx4){0.f, 0.f, 0.f, 0.f};

    for (int k0 = 0; k0 < KDIM; k0 += TK) {
        __syncthreads();   // previous tile consumed
#pragma unroll
        for (int is = 0; is < 4; ++is) {
            const int r  = w * 8 + is * 32 + srow;            // local row 0..127
            const int kk = k0 + ((schk ^ (r & 7)) << 3);      // swizzled global chunk
            async16(Abf + (size_t)(i0 + r) * KDIM + kk, &sA[(w * 8 + is * 32) * TK]);
            async16(XT  + (size_t)(b * DH + r) * KDIM + kk, &sX[(w * 8 + is * 32) * TK]);
        }
        __syncthreads();   // DMA landed (compiler drains vmcnt before barrier)

#pragma unroll
        for (int h = 0; h < 2; ++h) {
            short8 af[4], bf[4];
#pragma unroll
            for (int mi = 0; mi < 4; ++mi) {
                const int row = wm + mi * 16 + l15;
                af[mi] = *(const short8*)&sA[row * TK + (((h * 4 + q) ^ (l15 & 7)) << 3)];
            }
#pragma unroll
            for (int ni = 0; ni < 4; ++ni) {
                const int row = wn + ni * 16 + l15;
                bf[ni] = *(const short8*)&sX[row * TK + (((h * 4 + q) ^ (l15 & 7)) << 3)];
            }
#pragma unroll
            for (int mi = 0; mi < 4; ++mi)
#pragma unroll
                for (int ni = 0; ni < 4; ++ni)
                    acc[mi][ni] = __builtin_amdgcn_mfma_f32_16x16x32_bf16(
                        af[mi], bf[ni], acc[mi][ni], 0, 0, 0);
        }
    }

    // epilogue: + GCB (fp32), relu, permuted store out[b, s=i&63, t=i>>6, d]
#pragma unroll
    for (int mi = 0; mi < 4; ++mi) {
        const int ibase = i0 + wm + mi * 16 + q * 4;   // C/D: row = q*4 + reg
#pragma unroll
        for (int ni = 0; ni < 4; ++ni) {
            const int d = wn + ni * 16 + l15;          // C/D: col = lane&15
#pragma unroll
            for (int r = 0; r < 4; ++r) {
                const int i = ibase + r;
                float v = acc[mi][ni][r] + gcb[(size_t)i * DH + d];
                v = v > 0.f ? v : 0.f;
                out[(((size_t)b * NS + (i & 63)) * NT + (i >> 6)) * DH + d] = v;
            }
        }
    }
}

// ---- fallback: fused kernel (used only if ws too small) ----
#define APAD 40
#define XPAD 20
__global__ __launch_bounds__(256, 2)
void gcn_fused(const float* __restrict__ hmat, const float* __restrict__ aam,
               const float* __restrict__ gcw, const float* __restrict__ gcb,
               float* __restrict__ out)
{
    __shared__ short sA[TM * APAD];
    __shared__ unsigned int sX[DH * XPAD];
    const int tid = threadIdx.x;
    const int bid = blockIdx.x;
    const int mp  = (bid & 7) * 4 + (bid >> 7);
    const int b   = (bid >> 3) & 15;
    const int i0  = mp * TM;
    const int lane = tid & 63;
    const int wm = ((tid >> 6) >> 1) * 64;
    const int wn = ((tid >> 6) & 1) * 64;
    const int l15 = lane & 15;
    const int q   = lane >> 4;
    floatx4 acc[4][4];
#pragma unroll
    for (int mi = 0; mi < 4; ++mi)
#pragma unroll
        for (int ni = 0; ni < 4; ++ni) acc[mi][ni] = (floatx4){0.f,0.f,0.f,0.f};
    const int ar = tid >> 2, ac = (tid & 3) << 3;
    const int kp = tid >> 4, dg = (tid & 15) << 3;
    const int wkey = (tid & 3) << 2;
    for (int k0 = 0; k0 < KDIM; k0 += 32) {
        const size_t ga0 = (size_t)(i0 + ar) * KDIM + (k0 + ac);
        const size_t ga1 = ga0 + (size_t)64 * KDIM;
        floatx4 aa0a = *(const floatx4*)(aam + ga0), aa0b = *(const floatx4*)(aam + ga0 + 4);
        floatx4 ww0a = *(const floatx4*)(gcw + ga0), ww0b = *(const floatx4*)(gcw + ga0 + 4);
        floatx4 aa1a = *(const floatx4*)(aam + ga1), aa1b = *(const floatx4*)(aam + ga1 + 4);
        floatx4 ww1a = *(const floatx4*)(gcw + ga1), ww1b = *(const floatx4*)(gcw + ga1 + 4);
        const int jj = k0 + 2 * kp, tt = jj >> 6, cc = jj & 63;
        const size_t gx0 = ((size_t)(b * NC + cc) * NT + tt) * DH + dg;
        const size_t gx1 = gx0 + (size_t)NT * DH;
        floatx4 x0a = *(const floatx4*)(hmat + gx0), x0b = *(const floatx4*)(hmat + gx0 + 4);
        floatx4 x1a = *(const floatx4*)(hmat + gx1), x1b = *(const floatx4*)(hmat + gx1 + 4);
        __syncthreads();
        short8 p0, p1;
#pragma unroll
        for (int e = 0; e < 4; ++e) {
            float v0 = aa0a[e]*ww0a[e]; v0 = v0>0.f?v0:0.f;
            float v1 = aa0b[e]*ww0b[e]; v1 = v1>0.f?v1:0.f;
            float v2 = aa1a[e]*ww1a[e]; v2 = v2>0.f?v2:0.f;
            float v3 = aa1b[e]*ww1b[e]; v3 = v3>0.f?v3:0.f;
            p0[e] = (short)f2bf(v0); p0[e+4] = (short)f2bf(v1);
            p1[e] = (short)f2bf(v2); p1[e+4] = (short)f2bf(v3);
        }
        *(short8*)&sA[ar * APAD + ac] = p0;
        *(short8*)&sA[(ar + 64) * APAD + ac] = p1;
#pragma unroll
        for (int e = 0; e < 4; ++e) {
            unsigned int pka = (unsigned int)f2bf(x0a[e]) | ((unsigned int)f2bf(x1a[e]) << 16);
            unsigned int pkb = (unsigned int)f2bf(x0b[e]) | ((unsigned int)f2bf(x1b[e]) << 16);
            sX[(dg + e) * XPAD + (kp ^ wkey)] = pka;
            sX[(dg + e + 4) * XPAD + (kp ^ wkey)] = pkb;
        }
        __syncthreads();
        short8 afrag[4], bfrag[4];
#pragma unroll
        for (int mi = 0; mi < 4; ++mi)
            afrag[mi] = *(const short8*)&sA[(wm + mi * 16 + l15) * APAD + q * 8];
#pragma unroll
        for (int ni = 0; ni < 4; ++ni) {
            const int row = wn + ni * 16 + l15;
            const int col = (q * 4) ^ (((row >> 3) & 3) << 2);
            bfrag[ni] = *(const short8*)(sX + row * XPAD + col);
        }
#pragma unroll
        for (int mi = 0; mi < 4; ++mi)
#pragma unroll
            for (int ni = 0; ni < 4; ++ni)
                acc[mi][ni] = __builtin_amdgcn_mfma_f32_16x16x32_bf16(
                    afrag[mi], bfrag[ni], acc[mi][ni], 0, 0, 0);
    }
#pragma unroll
    for (int mi = 0; mi < 4; ++mi) {
        const int ibase = i0 + wm + mi * 16 + q * 4;
#pragma unroll
        for (int ni = 0; ni < 4; ++ni) {
            const int d = wn + ni * 16 + l15;
#pragma unroll
            for (int r = 0; r < 4; ++r) {
                const int i = ibase + r;
                float v = acc[mi][ni][r] + gcb[(size_t)i * DH + d];
                v = v > 0.f ? v : 0.f;
                out[(((size_t)b * NS + (i & 63)) * NT + (i >> 6)) * DH + d] = v;
            }
        }
    }
}

extern "C" void kernel_launch(void* const* d_in, const int* in_sizes, int n_in,
                              void* d_out, int out_size, void* d_ws, size_t ws_size,
                              hipStream_t stream) {
    const float* h   = (const float*)d_in[0];
    const float* aam = (const float*)d_in[2];
    const float* gcw = (const float*)d_in[3];
    const float* gcb = (const float*)d_in[4];
    float* out = (float*)d_out;

    const size_t A_BYTES  = (size_t)MDIM * KDIM * 2;            // 33.55 MB
    const size_t XT_BYTES = (size_t)BATCH * DH * KDIM * 2;      // 16.78 MB

    if (ws_size >= A_BYTES + XT_BYTES) {
        unsigned short* Abf = (unsigned short*)d_ws;
        unsigned short* XT  = (unsigned short*)((char*)d_ws + A_BYTES);
        prep<<<dim3(MDIM + BATCH * NT), 256, 0, stream>>>(aam, gcw, h, Abf, XT);
        gemm<<<dim3((MDIM / TM) * BATCH), 256, 0, stream>>>(Abf, XT, gcb, out);
    } else {
        gcn_fused<<<dim3((MDIM / TM) * BATCH), 256, 0, stream>>>(h, aam, gcw, gcb, out);
    }
}

// Round 2
// 236.969 us; speedup vs baseline: 1.1317x; 1.0550x over previous
//
#include <hip/hip_runtime.h>

// GCNFast: out[b,s,t,d] = relu( sum_j relu(AA[i%64,j%64]*GCW[i,j]) * X[j,b,d] + GCB[i,d] )
// 2 dispatches:
//   (1) fused prep (unchanged this round): A=relu(AA*GCW)->bf16 reading only the
//       64x64 AA tile; h -> XT bf16 [b*128+d][t*64+c] with coalesced writes.
//   (2) gemm REWRITTEN: triple-buffered counted-vmcnt pipeline (T3/T4/T5).
//       BM=128 x BN=256 tile (N=2048 contiguous), grid 256 = 1 block/CU,
//       512 thr / 8 waves, LDS 3x48KB. Loop: vmcnt(6) -> raw s_barrier ->
//       issue tile t+2 (6 global_load_lds) -> compute tile t. Loads stay in
//       flight across barriers (never drain to 0 in main loop). XOR chunk
//       swizzle kept (swizzled global src + linear LDS dest). np=bid&7 puts
//       one 2MB X-panel per XCD L2.
// Fallback to fused single-kernel path if ws_size < 50.3 MB.

#define NC 64
#define NS 64
#define NT 64
#define DH 128
#define BATCH 16
#define MDIM 4096
#define KDIM 4096
#define TM 128
#define TK 64
#define BM 128
#define BN 256
#define BK 64
#define NTILES (KDIM / BK)

typedef __attribute__((ext_vector_type(8))) short short8;
typedef __attribute__((ext_vector_type(4))) float floatx4;

__device__ __forceinline__ unsigned short f2bf(float f) {
    union { float f; unsigned int i; } v; v.f = f;
    return (unsigned short)((v.i + 0x7fffu + ((v.i >> 16) & 1u)) >> 16);
}
__device__ __forceinline__ void async16(const void* g, void* l) {
    __builtin_amdgcn_global_load_lds(
        (const __attribute__((address_space(1))) void*)g,
        (__attribute__((address_space(3))) void*)l, 16, 0, 0);
}

// ---- fused prep (UNCHANGED) ----
__global__ __launch_bounds__(256)
void prep(const float* __restrict__ aam, const float* __restrict__ gcw,
          const float* __restrict__ hmat,
          unsigned short* __restrict__ Abf, unsigned short* __restrict__ XT)
{
    const int tid = threadIdx.x;
    if ((int)blockIdx.x < MDIM) {
        const int i = blockIdx.x;
        __shared__ float sm[64];
        if (tid < 64) sm[tid] = aam[(size_t)(i & 63) * KDIM + tid];
        __syncthreads();
        const size_t base = (size_t)i * KDIM + tid * 16;
        floatx4 w0 = *(const floatx4*)(gcw + base);
        floatx4 w1 = *(const floatx4*)(gcw + base + 4);
        floatx4 w2 = *(const floatx4*)(gcw + base + 8);
        floatx4 w3 = *(const floatx4*)(gcw + base + 12);
        const float* m = &sm[(tid & 3) * 16];
        short8 p0, p1;
#pragma unroll
        for (int e = 0; e < 4; ++e) {
            float v0 = m[e]      * w0[e]; v0 = v0 > 0.f ? v0 : 0.f;
            float v1 = m[e + 4]  * w1[e]; v1 = v1 > 0.f ? v1 : 0.f;
            float v2 = m[e + 8]  * w2[e]; v2 = v2 > 0.f ? v2 : 0.f;
            float v3 = m[e + 12] * w3[e]; v3 = v3 > 0.f ? v3 : 0.f;
            p0[e]     = (short)f2bf(v0);
            p0[e + 4] = (short)f2bf(v1);
            p1[e]     = (short)f2bf(v2);
            p1[e + 4] = (short)f2bf(v3);
        }
        *(short8*)(Abf + base)     = p0;
        *(short8*)(Abf + base + 8) = p1;
    } else {
        const int blk = blockIdx.x - MDIM;
        const int b = blk >> 6;
        const int t = blk & 63;
        const int c0 = (tid & 7) * 8;
        const int d0 = tid >> 3;
#pragma unroll
        for (int it = 0; it < 4; ++it) {
            const int d = d0 + it * 32;
            short8 p;
#pragma unroll
            for (int e = 0; e < 8; ++e) {
                float v = hmat[(((size_t)b * NC + (c0 + e)) * NT + t) * DH + d];
                p[e] = (short)f2bf(v);
            }
            *(short8*)(XT + ((size_t)(b * DH + d)) * KDIM + t * 64 + c0) = p;
        }
    }
}

// ---- GEMM: C[4096, 2048] = A @ XT^T, triple-buffer + counted vmcnt ----
__global__ __launch_bounds__(512, 2)
void gemm(const unsigned short* __restrict__ Abf,
          const unsigned short* __restrict__ XT,
          const float* __restrict__ gcb,
          float* __restrict__ out)
{
    __shared__ short lds[3][(BM + BN) * BK];   // 3 x 48 KB = 144 KB

    const int tid = threadIdx.x;
    const int bid = blockIdx.x;
    const int np  = bid & 7;        // n-panel 0..7 -> one per XCD (X panel L2-fits)
    const int mp  = bid >> 3;       // m-panel 0..31
    const int i0  = mp * BM;
    const int n0  = np * BN;

    const int lane = tid & 63;
    const int w    = tid >> 6;          // 0..7
    const int wm   = (w >> 2) * 64;     // 2 M-warps
    const int wn   = (w & 3) * 64;      // 4 N-warps
    const int l15  = lane & 15;
    const int q    = lane >> 4;

    const int srow = lane >> 3;         // 0..7: row within 8-row group
    const int swz  = ((lane & 7) ^ srow) << 3;   // swizzled k-chunk (elements)

    const unsigned short* Ab = Abf + (size_t)i0 * KDIM + swz;
    const unsigned short* Xb = XT  + (size_t)n0 * KDIM + swz;

    floatx4 acc[4][4];
#pragma unroll
    for (int mi = 0; mi < 4; ++mi)
#pragma unroll
        for (int ni = 0; ni < 4; ++ni)
            acc[mi][ni] = (floatx4){0.f, 0.f, 0.f, 0.f};

    // issue 6 global_load_lds for tile t into buffer b (linear LDS dest,
    // swizzle carried on the per-lane GLOBAL source address)
    auto stage = [&](int t, int b) {
        const int k0 = t * BK;
        short* dst = lds[b];
#pragma unroll
        for (int ii = 0; ii < 2; ++ii) {           // A: 128 rows, 2 rounds
            const int r = ii * 64 + w * 8 + srow;
            async16(Ab + (size_t)r * KDIM + k0, dst + (ii * 64 + w * 8) * BK);
        }
#pragma unroll
        for (int ii = 0; ii < 4; ++ii) {           // X: 256 rows, 4 rounds
            const int r = ii * 64 + w * 8 + srow;
            async16(Xb + (size_t)r * KDIM + k0, dst + (BM + ii * 64 + w * 8) * BK);
        }
    };

    auto compute = [&](int b) {
        const short* sA = lds[b];
        const short* sX = lds[b] + BM * BK;
#pragma unroll
        for (int h = 0; h < 2; ++h) {
            const int co = ((h * 4 + q) ^ (l15 & 7)) << 3;
            short8 af[4], xf[4];
#pragma unroll
            for (int mi = 0; mi < 4; ++mi)
                af[mi] = *(const short8*)&sA[(wm + mi * 16 + l15) * BK + co];
#pragma unroll
            for (int ni = 0; ni < 4; ++ni)
                xf[ni] = *(const short8*)&sX[(wn + ni * 16 + l15) * BK + co];
            __builtin_amdgcn_s_setprio(1);
#pragma unroll
            for (int mi = 0; mi < 4; ++mi)
#pragma unroll
                for (int ni = 0; ni < 4; ++ni)
                    acc[mi][ni] = __builtin_amdgcn_mfma_f32_16x16x32_bf16(
                        af[mi], xf[ni], acc[mi][ni], 0, 0, 0);
            __builtin_amdgcn_s_setprio(0);
        }
    };

    stage(0, 0);
    stage(1, 1);

    int bc = 0;   // buffer holding tile t
    for (int t = 0; t < NTILES - 1; ++t) {
        // own tile-t loads retired; tile-(t+1)'s 6 stay in flight
        asm volatile("s_waitcnt vmcnt(6)" ::: "memory");
        __builtin_amdgcn_s_barrier();
        asm volatile("" ::: "memory");
        int bs = bc + 2; if (bs >= 3) bs -= 3;
        if (t + 2 < NTILES) stage(t + 2, bs);
        compute(bc);
        if (++bc == 3) bc = 0;
    }
    asm volatile("s_waitcnt vmcnt(0)" ::: "memory");
    __builtin_amdgcn_s_barrier();
    asm volatile("" ::: "memory");
    compute(bc);

    // epilogue: + GCB (fp32), relu, permuted store out[b, s=i&63, t=i>>6, d]
#pragma unroll
    for (int mi = 0; mi < 4; ++mi) {
        const int ibase = i0 + wm + mi * 16 + q * 4;   // C/D: row = q*4 + reg
#pragma unroll
        for (int ni = 0; ni < 4; ++ni) {
            const int n  = n0 + wn + ni * 16 + l15;    // global col 0..2047
            const int bb = n >> 7;
            const int d  = n & 127;
#pragma unroll
            for (int r = 0; r < 4; ++r) {
                const int i = ibase + r;
                float v = acc[mi][ni][r] + gcb[(size_t)i * DH + d];
                v = v > 0.f ? v : 0.f;
                out[(((size_t)bb * NS + (i & 63)) * NT + (i >> 6)) * DH + d] = v;
            }
        }
    }
}

// ---- fallback: fused kernel (used only if ws too small) ----
#define APAD 40
#define XPAD 20
__global__ __launch_bounds__(256, 2)
void gcn_fused(const float* __restrict__ hmat, const float* __restrict__ aam,
               const float* __restrict__ gcw, const float* __restrict__ gcb,
               float* __restrict__ out)
{
    __shared__ short sA[TM * APAD];
    __shared__ unsigned int sX[DH * XPAD];
    const int tid = threadIdx.x;
    const int bid = blockIdx.x;
    const int mp  = (bid & 7) * 4 + (bid >> 7);
    const int b   = (bid >> 3) & 15;
    const int i0  = mp * TM;
    const int lane = tid & 63;
    const int wm = ((tid >> 6) >> 1) * 64;
    const int wn = ((tid >> 6) & 1) * 64;
    const int l15 = lane & 15;
    const int q   = lane >> 4;
    floatx4 acc[4][4];
#pragma unroll
    for (int mi = 0; mi < 4; ++mi)
#pragma unroll
        for (int ni = 0; ni < 4; ++ni) acc[mi][ni] = (floatx4){0.f,0.f,0.f,0.f};
    const int ar = tid >> 2, ac = (tid & 3) << 3;
    const int kp = tid >> 4, dg = (tid & 15) << 3;
    const int wkey = (tid & 3) << 2;
    for (int k0 = 0; k0 < KDIM; k0 += 32) {
        const size_t ga0 = (size_t)(i0 + ar) * KDIM + (k0 + ac);
        const size_t ga1 = ga0 + (size_t)64 * KDIM;
        floatx4 aa0a = *(const floatx4*)(aam + ga0), aa0b = *(const floatx4*)(aam + ga0 + 4);
        floatx4 ww0a = *(const floatx4*)(gcw + ga0), ww0b = *(const floatx4*)(gcw + ga0 + 4);
        floatx4 aa1a = *(const floatx4*)(aam + ga1), aa1b = *(const floatx4*)(aam + ga1 + 4);
        floatx4 ww1a = *(const floatx4*)(gcw + ga1), ww1b = *(const floatx4*)(gcw + ga1 + 4);
        const int jj = k0 + 2 * kp, tt = jj >> 6, cc = jj & 63;
        const size_t gx0 = ((size_t)(b * NC + cc) * NT + tt) * DH + dg;
        const size_t gx1 = gx0 + (size_t)NT * DH;
        floatx4 x0a = *(const floatx4*)(hmat + gx0), x0b = *(const floatx4*)(hmat + gx0 + 4);
        floatx4 x1a = *(const floatx4*)(hmat + gx1), x1b = *(const floatx4*)(hmat + gx1 + 4);
        __syncthreads();
        short8 p0, p1;
#pragma unroll
        for (int e = 0; e < 4; ++e) {
            float v0 = aa0a[e]*ww0a[e]; v0 = v0>0.f?v0:0.f;
            float v1 = aa0b[e]*ww0b[e]; v1 = v1>0.f?v1:0.f;
            float v2 = aa1a[e]*ww1a[e]; v2 = v2>0.f?v2:0.f;
            float v3 = aa1b[e]*ww1b[e]; v3 = v3>0.f?v3:0.f;
            p0[e] = (short)f2bf(v0); p0[e+4] = (short)f2bf(v1);
            p1[e] = (short)f2bf(v2); p1[e+4] = (short)f2bf(v3);
        }
        *(short8*)&sA[ar * APAD + ac] = p0;
        *(short8*)&sA[(ar + 64) * APAD + ac] = p1;
#pragma unroll
        for (int e = 0; e < 4; ++e) {
            unsigned int pka = (unsigned int)f2bf(x0a[e]) | ((unsigned int)f2bf(x1a[e]) << 16);
            unsigned int pkb = (unsigned int)f2bf(x0b[e]) | ((unsigned int)f2bf(x1b[e]) << 16);
            sX[(dg + e) * XPAD + (kp ^ wkey)] = pka;
            sX[(dg + e + 4) * XPAD + (kp ^ wkey)] = pkb;
        }
        __syncthreads();
        short8 afrag[4], bfrag[4];
#pragma unroll
        for (int mi = 0; mi < 4; ++mi)
            afrag[mi] = *(const short8*)&sA[(wm + mi * 16 + l15) * APAD + q * 8];
#pragma unroll
        for (int ni = 0; ni < 4; ++ni) {
            const int row = wn + ni * 16 + l15;
            const int col = (q * 4) ^ (((row >> 3) & 3) << 2);
            bfrag[ni] = *(const short8*)(sX + row * XPAD + col);
        }
#pragma unroll
        for (int mi = 0; mi < 4; ++mi)
#pragma unroll
            for (int ni = 0; ni < 4; ++ni)
                acc[mi][ni] = __builtin_amdgcn_mfma_f32_16x16x32_bf16(
                    afrag[mi], bfrag[ni], acc[mi][ni], 0, 0, 0);
    }
#pragma unroll
    for (int mi = 0; mi < 4; ++mi) {
        const int ibase = i0 + wm + mi * 16 + q * 4;
#pragma unroll
        for (int ni = 0; ni < 4; ++ni) {
            const int d = wn + ni * 16 + l15;
#pragma unroll
            for (int r = 0; r < 4; ++r) {
                const int i = ibase + r;
                float v = acc[mi][ni][r] + gcb[(size_t)i * DH + d];
                v = v > 0.f ? v : 0.f;
                out[(((size_t)b * NS + (i & 63)) * NT + (i >> 6)) * DH + d] = v;
            }
        }
    }
}

extern "C" void kernel_launch(void* const* d_in, const int* in_sizes, int n_in,
                              void* d_out, int out_size, void* d_ws, size_t ws_size,
                              hipStream_t stream) {
    const float* h   = (const float*)d_in[0];
    const float* aam = (const float*)d_in[2];
    const float* gcw = (const float*)d_in[3];
    const float* gcb = (const float*)d_in[4];
    float* out = (float*)d_out;

    const size_t A_BYTES  = (size_t)MDIM * KDIM * 2;            // 33.55 MB
    const size_t XT_BYTES = (size_t)BATCH * DH * KDIM * 2;      // 16.78 MB

    if (ws_size >= A_BYTES + XT_BYTES) {
        unsigned short* Abf = (unsigned short*)d_ws;
        unsigned short* XT  = (unsigned short*)((char*)d_ws + A_BYTES);
        prep<<<dim3(MDIM + BATCH * NT), 256, 0, stream>>>(aam, gcw, h, Abf, XT);
        gemm<<<dim3((MDIM / BM) * (BATCH * DH / BN)), 512, 0, stream>>>(Abf, XT, gcb, out);
    } else {
        gcn_fused<<<dim3((MDIM / TM) * BATCH), 256, 0, stream>>>(h, aam, gcw, gcb, out);
    }
}